// Round 5
// baseline (37.282 us; speedup 1.0000x reference)
//
#include <hip/hip_runtime.h>

// CPAB 1D warp + linear resample — two-kernel split:
//   A: ODE integrate (latency-bound, tiny traffic) -> p into d_ws
//   B: gather + lerp (pure streaming, full-occupancy memory phase)
// x:     [B, LIN, C]  f32   (d_in[0])
// theta: [B, D]       f32   (d_in[1])
// basis: [2*NC, D]    f32   (d_in[2])
// out:   [B, OUTLEN, C] f32

#define NSTEPS 64
#define NC     32
#define DD     33      // nC + 1
#define LIN    2048
#define CCH    32
#define OUTLEN 2048
#define JPW    64      // j positions per wave
#define WPB    4       // waves per block
#define JPB    (JPW * WPB)   // 256

typedef float f32x4 __attribute__((ext_vector_type(4)));

// ---------------- Kernel A: ODE integrate -> p ----------------
__global__ __launch_bounds__(256) void cpab_ode_kernel(
    const float* __restrict__ theta,
    const float* __restrict__ basis,
    float* __restrict__ pws)
{
    __shared__ float2 ctab[WPB][NC];    // (c1, c0): phi' = c1*phi + c0

    const int t    = threadIdx.x;
    const int wave = t >> 6;
    const int lane = t & 63;
    const int blocksPerB = OUTLEN / JPB;            // 8
    const int b = blockIdx.x / blocksPerB;
    const int j = (blockIdx.x % blocksPerB) * JPB + wave * JPW + lane;

    const float dt = 1.0f / (float)NSTEPS;

    // lane k computes A_k = basis[k,:] . theta[b,:]
    float acc = 0.0f;
    {
        const float* bs = basis + lane * DD;
        const float* th = theta + b * DD;
        #pragma unroll
        for (int d = 0; d < DD; ++d) acc = fmaf(bs[d], th[d], acc);
    }
    {
        int c = lane & (NC - 1);
        float a  = __shfl(acc, 2 * c);
        float bb = __shfl(acc, 2 * c + 1);
        if (lane < NC) ctab[wave][c] = make_float2(fmaf(a, dt, 1.0f), bb * dt);
    }
    // wave-private LDS: write->read ordered by lgkmcnt, no barrier needed

    float phi = (float)j * (1.0f / (float)(OUTLEN - 1));
    const float2* ct = ctab[wave];
    #pragma unroll
    for (int s = 0; s < NSTEPS; ++s) {
        float f = fminf(fmaxf(phi * (float)NC, 0.0f), (float)(NC - 1)); // v_med3
        float2 cc = ct[(int)f];
        phi = fmaf(cc.x, phi, cc.y);
    }
    // p in [0, 2047]; B derives i0/w from p alone
    pws[b * OUTLEN + j] = fminf(fmaxf(phi, 0.0f), 1.0f) * (float)(LIN - 1);
}

// ---------------- Kernel B: gather + lerp (streaming) ----------------
__global__ __launch_bounds__(256) void cpab_gather_kernel(
    const float* __restrict__ x,
    const float* __restrict__ pws,
    float* __restrict__ out)
{
    const int t    = threadIdx.x;
    const int wave = t >> 6;
    const int lane = t & 63;
    const int blocksPerB = OUTLEN / JPB;            // 8
    const int b     = blockIdx.x / blocksPerB;
    const int jbase = (blockIdx.x % blocksPerB) * JPB + wave * JPW;

    const f32x4* xb = (const f32x4*)(x + (size_t)b * (LIN * CCH));
    f32x4* ob = (f32x4*)(out + ((size_t)b * OUTLEN + jbase) * CCH);
    const float* pw = pws + b * OUTLEN + jbase;
    const int c4  = lane & 7;        // float4 column within row (32 ch = 8 float4)
    const int jl0 = lane >> 3;       // 0..7

    // hoist the 8 p loads (8-lane broadcast each; L1 handles)
    float p[8];
    #pragma unroll
    for (int it = 0; it < 8; ++it) p[it] = pw[it * 8 + jl0];

    #pragma unroll
    for (int it = 0; it < 8; ++it) {
        int   i0 = min((int)p[it], LIN - 2);     // p >= 0, trunc == floor
        float w  = p[it] - (float)i0;
        f32x4 g0 = xb[i0 * (CCH / 4) + c4];
        f32x4 g1 = xb[(i0 + 1) * (CCH / 4) + c4];
        ob[(it * 8 + jl0) * (CCH / 4) + c4] = g0 + w * (g1 - g0);
    }
}

// ---------------- Fallback: fused single kernel (R2, known-good) ----------------
__global__ __launch_bounds__(256) void cpab_fused_kernel(
    const float* __restrict__ x,
    const float* __restrict__ theta,
    const float* __restrict__ basis,
    float* __restrict__ out)
{
    __shared__ float2 ctab[WPB][NC];
    __shared__ float2 iw[WPB][JPW];

    const int t    = threadIdx.x;
    const int wave = t >> 6;
    const int lane = t & 63;
    const int blocksPerB = OUTLEN / JPB;
    const int b     = blockIdx.x / blocksPerB;
    const int jbase = (blockIdx.x % blocksPerB) * JPB + wave * JPW;
    const float dt = 1.0f / (float)NSTEPS;

    float acc = 0.0f;
    {
        const float* bs = basis + lane * DD;
        const float* th = theta + b * DD;
        #pragma unroll
        for (int d = 0; d < DD; ++d) acc = fmaf(bs[d], th[d], acc);
    }
    {
        int c = lane & (NC - 1);
        float a  = __shfl(acc, 2 * c);
        float bb = __shfl(acc, 2 * c + 1);
        if (lane < NC) ctab[wave][c] = make_float2(fmaf(a, dt, 1.0f), bb * dt);
    }
    {
        const int j = jbase + lane;
        float phi = (float)j * (1.0f / (float)(OUTLEN - 1));
        const float2* ct = ctab[wave];
        #pragma unroll
        for (int s = 0; s < NSTEPS; ++s) {
            float f = fminf(fmaxf(phi * (float)NC, 0.0f), (float)(NC - 1));
            float2 cc = ct[(int)f];
            phi = fmaf(cc.x, phi, cc.y);
        }
        float p = fminf(fmaxf(phi, 0.0f), 1.0f) * (float)(LIN - 1);
        int i0 = min(max((int)p, 0), LIN - 2);
        iw[wave][lane] = make_float2(p - (float)i0, (float)i0);
    }
    const f32x4* xb = (const f32x4*)(x + (size_t)b * (LIN * CCH));
    f32x4* ob = (f32x4*)(out + ((size_t)b * OUTLEN + jbase) * CCH);
    const int c4  = lane & 7;
    const int jl0 = lane >> 3;
    float2 f[8];
    #pragma unroll
    for (int it = 0; it < 8; ++it) f[it] = iw[wave][it * 8 + jl0];
    #pragma unroll
    for (int it = 0; it < 8; ++it) {
        int   i0 = (int)f[it].y;
        float w  = f[it].x;
        f32x4 g0 = xb[i0 * (CCH / 4) + c4];
        f32x4 g1 = xb[(i0 + 1) * (CCH / 4) + c4];
        ob[(it * 8 + jl0) * (CCH / 4) + c4] = g0 + w * (g1 - g0);
    }
}

extern "C" void kernel_launch(void* const* d_in, const int* in_sizes, int n_in,
                              void* d_out, int out_size, void* d_ws, size_t ws_size,
                              hipStream_t stream) {
    const float* x     = (const float*)d_in[0];
    const float* theta = (const float*)d_in[1];
    const float* basis = (const float*)d_in[2];
    float* out = (float*)d_out;

    const int B = in_sizes[1] / DD;                 // 256
    const int grid = B * (OUTLEN / JPB);            // 2048 blocks
    const size_t need = (size_t)B * OUTLEN * sizeof(float);   // 2 MB

    if (ws_size >= need) {
        float* pws = (float*)d_ws;
        cpab_ode_kernel<<<grid, 256, 0, stream>>>(theta, basis, pws);
        cpab_gather_kernel<<<grid, 256, 0, stream>>>(x, pws, out);
    } else {
        cpab_fused_kernel<<<grid, 256, 0, stream>>>(x, theta, basis, out);
    }
}

// Round 6
// 28.687 us; speedup vs baseline: 1.2996x; 1.2996x over previous
//
#include <hip/hip_runtime.h>

// CPAB 1D warp + linear resample — fused (R2 structure), phase-2 rebuilt:
//   * all 16 gather loads explicitly staged in registers (max wave-MLP)
//   * nontemporal stores for out (no L2 write-allocate; keep x resident)
// x:     [B, LIN, C]  f32   (d_in[0])
// theta: [B, D]       f32   (d_in[1])
// basis: [2*NC, D]    f32   (d_in[2])
// out:   [B, OUTLEN, C] f32

#define NSTEPS 64
#define NC     32
#define DD     33      // nC + 1
#define LIN    2048
#define CCH    32
#define OUTLEN 2048
#define JPW    64      // j positions per wave
#define WPB    4       // waves per block
#define JPB    (JPW * WPB)   // 256

typedef float f32x4 __attribute__((ext_vector_type(4)));

__global__ __launch_bounds__(256) void cpab_warp_kernel(
    const float* __restrict__ x,
    const float* __restrict__ theta,
    const float* __restrict__ basis,
    float* __restrict__ out)
{
    // wave-private LDS: same-wave write->read ordered by lgkmcnt, no barrier
    __shared__ float2 ctab[WPB][NC];    // (c1, c0) per cell: phi' = c1*phi + c0
    __shared__ float2 iw[WPB][JPW];     // (w, i0) per j

    const int t    = threadIdx.x;
    const int wave = t >> 6;
    const int lane = t & 63;
    const int blocksPerB = OUTLEN / JPB;            // 8
    const int b     = blockIdx.x / blocksPerB;
    const int jbase = (blockIdx.x % blocksPerB) * JPB + wave * JPW;

    const float dt = 1.0f / (float)NSTEPS;

    // Phase 0 (per wave): lane k computes A_k = basis[k,:] . theta[b,:]
    float acc = 0.0f;
    {
        const float* bs = basis + lane * DD;
        const float* th = theta + b * DD;
        #pragma unroll
        for (int d = 0; d < DD; ++d) acc = fmaf(bs[d], th[d], acc);
    }
    {
        // cell c: a = A[2c], b = A[2c+1]  ->  c1 = 1 + a*dt, c0 = b*dt
        int c = lane & (NC - 1);
        float a  = __shfl(acc, 2 * c);
        float bb = __shfl(acc, 2 * c + 1);
        if (lane < NC) ctab[wave][c] = make_float2(fmaf(a, dt, 1.0f), bb * dt);
    }

    // Phase 1 (per wave): integrate one trajectory per lane
    {
        const int j = jbase + lane;
        float phi = (float)j * (1.0f / (float)(OUTLEN - 1));
        const float2* ct = ctab[wave];
        #pragma unroll
        for (int s = 0; s < NSTEPS; ++s) {
            // truncation == floor after clamp-to-[0,31] (negatives clamp to 0)
            float f = fminf(fmaxf(phi * (float)NC, 0.0f), (float)(NC - 1)); // v_med3
            float2 cc = ct[(int)f];
            phi = fmaf(cc.x, phi, cc.y);
        }
        float p = fminf(fmaxf(phi, 0.0f), 1.0f) * (float)(LIN - 1);
        int i0 = min(max((int)p, 0), LIN - 2);   // p >= 0 so trunc == floor
        iw[wave][lane] = make_float2(p - (float)i0, (float)i0);
    }

    // Phase 2 (per wave): resample 64 j x 32 c as f32x4, 8 its.
    // Stage ALL 16 loads in registers first -> 16 loads in flight per wave.
    const f32x4* xb = (const f32x4*)(x + (size_t)b * (LIN * CCH));
    f32x4* ob = (f32x4*)(out + ((size_t)b * OUTLEN + jbase) * CCH);
    const int c4  = lane & 7;        // f32x4 column within row (32 ch = 8 f32x4)
    const int jl0 = lane >> 3;       // 0..7

    float2 f[8];
    #pragma unroll
    for (int it = 0; it < 8; ++it) f[it] = iw[wave][it * 8 + jl0];

    f32x4 g0[8], g1[8];
    #pragma unroll
    for (int it = 0; it < 8; ++it) {
        int i0 = (int)f[it].y;
        g0[it] = xb[i0 * (CCH / 4) + c4];
        g1[it] = xb[(i0 + 1) * (CCH / 4) + c4];
    }
    #pragma unroll
    for (int it = 0; it < 8; ++it) {
        float w = f[it].x;
        f32x4 r = g0[it] + w * (g1[it] - g0[it]);
        __builtin_nontemporal_store(r, &ob[(it * 8 + jl0) * (CCH / 4) + c4]);
    }
}

extern "C" void kernel_launch(void* const* d_in, const int* in_sizes, int n_in,
                              void* d_out, int out_size, void* d_ws, size_t ws_size,
                              hipStream_t stream) {
    const float* x     = (const float*)d_in[0];
    const float* theta = (const float*)d_in[1];
    const float* basis = (const float*)d_in[2];
    float* out = (float*)d_out;

    const int B = in_sizes[1] / DD;                 // 256
    const int grid = B * (OUTLEN / JPB);            // 2048 blocks
    cpab_warp_kernel<<<grid, 256, 0, stream>>>(x, theta, basis, out);
}

// Round 7
// 28.336 us; speedup vs baseline: 1.3157x; 1.0124x over previous
//
#include <hip/hip_runtime.h>

// CPAB 1D warp + linear resample — fused, phase-2 MLP forced:
//   * 16 gather loads staged and FENCED (sched_barrier) -> all in flight
//   * nontemporal stores for out (keeps x resident in L2; FETCH 52->30MB)
//   * q-scaled ODE: one fewer VALU op in the 64-step dependent chain
// x:     [B, LIN, C]  f32   (d_in[0])
// theta: [B, D]       f32   (d_in[1])
// basis: [2*NC, D]    f32   (d_in[2])
// out:   [B, OUTLEN, C] f32

#define NSTEPS 64
#define NC     32
#define DD     33      // nC + 1
#define LIN    2048
#define CCH    32
#define OUTLEN 2048
#define JPW    64      // j positions per wave
#define WPB    4       // waves per block
#define JPB    (JPW * WPB)   // 256

typedef float f32x4 __attribute__((ext_vector_type(4)));

__global__ __launch_bounds__(256) void cpab_warp_kernel(
    const float* __restrict__ x,
    const float* __restrict__ theta,
    const float* __restrict__ basis,
    float* __restrict__ out)
{
    // wave-private LDS: same-wave write->read ordered by lgkmcnt, no barrier
    __shared__ float2 ctab[WPB][NC];    // (c1, c0*NC) per cell: q' = c1*q + c0n
    __shared__ float2 iw[WPB][JPW];     // (w, i0) per j

    const int t    = threadIdx.x;
    const int wave = t >> 6;
    const int lane = t & 63;
    const int blocksPerB = OUTLEN / JPB;            // 8
    const int b     = blockIdx.x / blocksPerB;
    const int jbase = (blockIdx.x % blocksPerB) * JPB + wave * JPW;

    const float dt = 1.0f / (float)NSTEPS;

    // Phase 0 (per wave): lane k computes A_k = basis[k,:] . theta[b,:]
    float acc = 0.0f;
    {
        const float* bs = basis + lane * DD;
        const float* th = theta + b * DD;
        #pragma unroll
        for (int d = 0; d < DD; ++d) acc = fmaf(bs[d], th[d], acc);
    }
    {
        // cell c: a = A[2c], b = A[2c+1] -> c1 = 1 + a*dt, c0n = b*dt*NC
        int c = lane & (NC - 1);
        float a  = __shfl(acc, 2 * c);
        float bb = __shfl(acc, 2 * c + 1);
        if (lane < NC) ctab[wave][c] = make_float2(fmaf(a, dt, 1.0f), bb * dt * (float)NC);
    }

    // Phase 1 (per wave): integrate one trajectory per lane, q = phi*NC
    {
        const int j = jbase + lane;
        float q = (float)j * ((float)NC / (float)(OUTLEN - 1));
        const float2* ct = ctab[wave];
        #pragma unroll
        for (int s = 0; s < NSTEPS; ++s) {
            // cell = trunc(clamp(q,0,31)) == reference clip(floor(phi*NC),0,31)
            float f = fminf(fmaxf(q, 0.0f), (float)(NC - 1));   // v_med3
            float2 cc = ct[(int)f];
            q = fmaf(cc.x, q, cc.y);
        }
        // p = clamp(phi,0,1)*(LIN-1) with phi = q/NC
        float p = fminf(fmaxf(q * ((float)(LIN - 1) / (float)NC), 0.0f), (float)(LIN - 1));
        int i0 = min((int)p, LIN - 2);           // p >= 0, trunc == floor
        iw[wave][lane] = make_float2(p - (float)i0, (float)i0);
    }

    // Phase 2 (per wave): resample 64 j x 32 c as f32x4, 8 its.
    // Issue ALL 16 loads, fence the scheduler, then lerp + NT-store.
    const f32x4* xb = (const f32x4*)(x + (size_t)b * (LIN * CCH));
    f32x4* ob = (f32x4*)(out + ((size_t)b * OUTLEN + jbase) * CCH);
    const int c4  = lane & 7;        // f32x4 column within row (32 ch = 8 f32x4)
    const int jl0 = lane >> 3;       // 0..7

    float2 f[8];
    #pragma unroll
    for (int it = 0; it < 8; ++it) f[it] = iw[wave][it * 8 + jl0];

    f32x4 g0[8], g1[8];
    #pragma unroll
    for (int it = 0; it < 8; ++it) {
        int i0 = (int)f[it].y;
        g0[it] = xb[i0 * (CCH / 4) + c4];
        g1[it] = xb[(i0 + 1) * (CCH / 4) + c4];
    }
    __builtin_amdgcn_sched_barrier(0);   // keep all 16 loads issued before any use

    #pragma unroll
    for (int it = 0; it < 8; ++it) {
        float w = f[it].x;
        f32x4 r = g0[it] + w * (g1[it] - g0[it]);
        __builtin_nontemporal_store(r, &ob[(it * 8 + jl0) * (CCH / 4) + c4]);
    }
}

extern "C" void kernel_launch(void* const* d_in, const int* in_sizes, int n_in,
                              void* d_out, int out_size, void* d_ws, size_t ws_size,
                              hipStream_t stream) {
    const float* x     = (const float*)d_in[0];
    const float* theta = (const float*)d_in[1];
    const float* basis = (const float*)d_in[2];
    float* out = (float*)d_out;

    const int B = in_sizes[1] / DD;                 // 256
    const int grid = B * (OUTLEN / JPB);            // 2048 blocks
    cpab_warp_kernel<<<grid, 256, 0, stream>>>(x, theta, basis, out);
}